// Round 11
// baseline (182.738 us; speedup 1.0000x reference)
//
#include <hip/hip_runtime.h>
#include <hip/hip_bf16.h>

#define B_NUM 2
#define T_SEQ 2048
#define C_DIM 1024
#define H_NUM 16
#define HD    64
#define M_TOT 4096
#define BH_N  32

typedef __attribute__((ext_vector_type(8))) short short8;     // 8 bf16
typedef __attribute__((ext_vector_type(4))) float floatx4;    // 4 fp32
typedef __attribute__((ext_vector_type(16))) float floatx16;  // 16 fp32 acc

__device__ __forceinline__ short f2bf(float f) {
    unsigned u = __float_as_uint(f);
    u += 0x7FFFu + ((u >> 16) & 1u);
    return (short)(u >> 16);
}

__device__ __forceinline__ unsigned pk2bf(float a, float b) {
    float2 f2; f2.x = a; f2.y = b;
    __hip_bfloat162 h = __float22bfloat162_rn(f2);
    unsigned u; __builtin_memcpy(&u, &h, 4); return u;
}

// async global->LDS, 16B per lane; LDS dest = wave-uniform base + lane*16
__device__ __forceinline__ void gld16(const short* g, short* l) {
    __builtin_amdgcn_global_load_lds(
        (const __attribute__((address_space(1))) void*)g,
        (__attribute__((address_space(3))) void*)l, 16, 0, 0);
}

// ---------------------------------------------------------------------------
// Fused preprocessing. grid 3072 x 256.
// ---------------------------------------------------------------------------
__global__ __launch_bounds__(256) void prep_k(
    const float* __restrict__ x, const float* __restrict__ Wq,
    const float* __restrict__ Wk, const float* __restrict__ Wv,
    const float* __restrict__ Wp,
    short* __restrict__ xb, short* __restrict__ wt, short* __restrict__ wpt) {
    const int bid = blockIdx.x;
    const int tid = threadIdx.x;
    if (bid < 2048) {
        int idx = (bid * 256 + tid) * 8;
        float4 a = *(const float4*)(x + idx);
        float4 b = *(const float4*)(x + idx + 4);
        short8 o;
        o[0] = f2bf(a.x); o[1] = f2bf(a.y); o[2] = f2bf(a.z); o[3] = f2bf(a.w);
        o[4] = f2bf(b.x); o[5] = f2bf(b.y); o[6] = f2bf(b.z); o[7] = f2bf(b.w);
        *(short8*)(xb + idx) = o;
        return;
    }
    const int b2 = bid - 2048;
    const int ct = b2 & 15, y = b2 >> 4;
    __shared__ short sh[64][72];
    if (y < 48) {
        const int which = y >> 4, h = y & 15;
        const float* W = ((which == 0) ? Wq : (which == 1) ? Wk : Wv) + (size_t)h * C_DIM * HD;
        const int c0 = ct * 64;
        #pragma unroll
        for (int p = 0; p < 4; ++p) {
            int idx = tid + 256 * p;
            int c = idx >> 4, d4 = idx & 15;
            float4 v = *(const float4*)(W + (size_t)(c0 + c) * HD + d4 * 4);
            sh[d4 * 4 + 0][c] = f2bf(v.x);
            sh[d4 * 4 + 1][c] = f2bf(v.y);
            sh[d4 * 4 + 2][c] = f2bf(v.z);
            sh[d4 * 4 + 3][c] = f2bf(v.w);
        }
        __syncthreads();
        #pragma unroll
        for (int p = 0; p < 2; ++p) {
            int idx = tid + 256 * p;
            int d = idx >> 3, cc = idx & 7;
            short8 vv = *(const short8*)(&sh[d][cc * 8]);
            *(short8*)(wt + ((size_t)(which * 16 + h) * 64 + d) * C_DIM + c0 + cc * 8) = vv;
        }
    } else {
        const int nt = y - 48;
        #pragma unroll
        for (int p = 0; p < 4; ++p) {
            int idx = tid + 256 * p;
            int k = idx >> 4, n4 = idx & 15;
            float4 v = *(const float4*)(Wp + (size_t)(ct * 64 + k) * C_DIM + nt * 64 + n4 * 4);
            sh[n4 * 4 + 0][k] = f2bf(v.x);
            sh[n4 * 4 + 1][k] = f2bf(v.y);
            sh[n4 * 4 + 2][k] = f2bf(v.z);
            sh[n4 * 4 + 3][k] = f2bf(v.w);
        }
        __syncthreads();
        #pragma unroll
        for (int p = 0; p < 2; ++p) {
            int idx = tid + 256 * p;
            int n = idx >> 3, cc = idx & 7;
            short8 vv = *(const short8*)(&sh[n][cc * 8]);
            *(short8*)(wpt + (size_t)(nt * 64 + n) * C_DIM + ct * 64 + cc * 8) = vv;
        }
    }
}

// ---------------------------------------------------------------------------
// Fused QKV GEMM (m97-style). Tile 128x128, BK=64. grid (32, 24).
// ---------------------------------------------------------------------------
__global__ __launch_bounds__(256) void qkv_k(
    const short* __restrict__ xb, const short* __restrict__ wt,
    short* __restrict__ qb, short* __restrict__ kb, short* __restrict__ vtb) {
    const int mt = blockIdx.x, ntg = blockIdx.y;
    const int m0 = mt * 128, n0 = ntg * 128;
    const int which = ntg >> 3;
    const float sc = (which == 0) ? 0.125f * 1.4426950408889634f : 1.0f;

    __shared__ short smem[17408];
    short* As = smem;
    short* Bs = smem + 8192;

    const int tid = threadIdx.x;
    const int lane = tid & 63, w = tid >> 6;
    const int wm = w & 1, wn = w >> 1;
    const int hi = lane >> 4, llo = lane & 15;
    const int lrow = lane >> 3;
    const int lswz = ((lane & 7) ^ (lrow & 7)) * 8;
    const int fc0 = (hi ^ (llo & 7)) * 8;
    const int fc1 = ((hi + 4) ^ (llo & 7)) * 8;

    floatx4 acc[4][4];
    #pragma unroll
    for (int i = 0; i < 4; ++i)
        #pragma unroll
        for (int j = 0; j < 4; ++j)
            #pragma unroll
            for (int r = 0; r < 4; ++r) acc[i][j][r] = 0.0f;

    const size_t a_base = (size_t)(m0 + w * 32 + lrow) * C_DIM + lswz;
    const size_t b_base = (size_t)(n0 + w * 32 + lrow) * C_DIM + lswz;

    for (int kt = 0; kt < C_DIM / 64; ++kt) {
        const int c0 = kt * 64;
        __syncthreads();
        #pragma unroll
        for (int p = 0; p < 4; ++p) {
            gld16(xb + a_base + (size_t)p * 8 * C_DIM + c0, &As[(w * 32 + p * 8) * 64]);
            gld16(wt + b_base + (size_t)p * 8 * C_DIM + c0, &Bs[(w * 32 + p * 8) * 64]);
        }
        __syncthreads();

        short8 af[4][2];
        #pragma unroll
        for (int mi = 0; mi < 4; ++mi) {
            const int row = wm * 64 + mi * 16 + llo;
            af[mi][0] = *(const short8*)(&As[row * 64 + fc0]);
            af[mi][1] = *(const short8*)(&As[row * 64 + fc1]);
        }
        #pragma unroll
        for (int ni = 0; ni < 4; ++ni) {
            const int row = wn * 64 + ni * 16 + llo;
            short8 b0 = *(const short8*)(&Bs[row * 64 + fc0]);
            short8 b1 = *(const short8*)(&Bs[row * 64 + fc1]);
            #pragma unroll
            for (int mi = 0; mi < 4; ++mi) {
                acc[mi][ni] = __builtin_amdgcn_mfma_f32_16x16x32_bf16(af[mi][0], b0, acc[mi][ni], 0, 0, 0);
                acc[mi][ni] = __builtin_amdgcn_mfma_f32_16x16x32_bf16(af[mi][1], b1, acc[mi][ni], 0, 0, 0);
            }
        }
    }
    __syncthreads();

    short (*R)[136] = (short(*)[136])smem;
    if (which == 2) {
        #pragma unroll
        for (int mi = 0; mi < 4; ++mi)
            #pragma unroll
            for (int ni = 0; ni < 4; ++ni)
                #pragma unroll
                for (int r = 0; r < 4; ++r)
                    R[wn * 64 + ni * 16 + llo][wm * 64 + mi * 16 + hi * 4 + r] =
                        f2bf(acc[mi][ni][r]);
        __syncthreads();
        const int b = m0 >> 11;
        #pragma unroll
        for (int p = 0; p < 8; ++p) {
            int idx = tid + 256 * p;
            int rr = idx >> 4, cc = idx & 15;
            short8 vv = *(const short8*)(&R[rr][cc * 8]);
            int n = n0 + rr;
            int h = (n >> 6) & 15, d = n & 63;
            int t = (m0 & 2047) + cc * 8;
            *(short8*)(vtb + ((size_t)((b * H_NUM + h) * HD + d)) * T_SEQ + t) = vv;
        }
    } else {
        short* outp = (which == 0) ? qb : kb;
        #pragma unroll
        for (int mi = 0; mi < 4; ++mi)
            #pragma unroll
            for (int ni = 0; ni < 4; ++ni)
                #pragma unroll
                for (int r = 0; r < 4; ++r)
                    R[wm * 64 + mi * 16 + hi * 4 + r][wn * 64 + ni * 16 + llo] =
                        f2bf(acc[mi][ni][r] * sc);
        __syncthreads();
        #pragma unroll
        for (int p = 0; p < 8; ++p) {
            int idx = tid + 256 * p;
            int r = idx >> 4, cc = idx & 15;
            short8 vv = *(const short8*)(&R[r][cc * 8]);
            int mg = m0 + r;
            int b = mg >> 11, t = mg & 2047;
            int n = n0 + cc * 8;
            int h = (n >> 6) & 15, d = n & 63;
            *(short8*)(outp + ((size_t)(b * H_NUM + h) * T_SEQ + t) * HD + d) = vv;
        }
    }
}

// ---------------------------------------------------------------------------
// Flash attention on mfma_f32_32x32x16_bf16, transposed dataflow.
// 256 threads / 4 waves; wave owns 32 q-cols (q-tile 128). Q stationary in
// registers (zero LDS B-traffic for S). l via per-lane VALU sum (linear in
// exp2-domain) + one shfl at the end. dbuf gld16 staging, 1 barrier/iter.
// A/B frag: [m|n = lane&31][k = (lane>>5)*8 + j]; C/D: col=lane&31,
// row=(reg&3)+8*(reg>>2)+4*(lane>>5)  [m74/m101].
// grid (bh=32, 16), qt = y<8 ? 15-y : y-8.
// ---------------------------------------------------------------------------
__global__ __launch_bounds__(256, 2) void attn_k(
    const short* __restrict__ qb, const short* __restrict__ kb,
    const short* __restrict__ vtb, short* __restrict__ attb) {
    const int bh = blockIdx.x;
    const int y = blockIdx.y;
    const int qt = (y < 8) ? (15 - y) : (y - 8);
    const int b = bh >> 4, h = bh & 15;
    const short* K  = kb  + (size_t)bh * T_SEQ * HD;    // [s][d]
    const short* Vt = vtb + (size_t)bh * HD * T_SEQ;    // [d][s]

    __shared__ short Ks[2][4096];      // [64][64] swizzled, dbuf
    __shared__ short Vs[2][4096];      // [64][64] swizzled, dbuf
    __shared__ short Ps[128][76];      // P^T as [q][s]; epilogue O[q][d]

    const int tid = threadIdx.x;
    const int lane = tid & 63, w = tid >> 6;            // 4 waves
    const int nq = lane & 31, kh2 = lane >> 5;          // n-col, k-half
    const int lrow = lane >> 3;
    const int lswz = ((lane & 7) ^ (lrow & 7)) * 8;
    const int kmax = 2 * qt + 1;
    const int qcol0 = qt * 128 + w * 32;

    // Q B-frags, stationary: B[k = t*16 + kh2*8 + j][n = nq]
    short8 qf[4];
    #pragma unroll
    for (int t = 0; t < 4; ++t)
        qf[t] = *(const short8*)(qb +
            ((size_t)bh * T_SEQ + qcol0 + nq) * HD + t * 16 + kh2 * 8);

    // preload tile 0 (wave stages 16 rows of K and of Vt)
    #pragma unroll
    for (int p = 0; p < 2; ++p) {
        gld16(K + (size_t)(w * 16 + p * 8 + lrow) * HD + lswz,
              &Ks[0][(w * 16 + p * 8) * 64]);
        gld16(Vt + (size_t)(w * 16 + p * 8 + lrow) * T_SEQ + lswz,
              &Vs[0][(w * 16 + p * 8) * 64]);
    }

    floatx16 Oa[2];
    #pragma unroll
    for (int dt = 0; dt < 2; ++dt)
        #pragma unroll
        for (int r = 0; r < 16; ++r) Oa[dt][r] = 0.0f;
    float l_acc = 0.0f;

    for (int kt = 0; kt <= kmax; ++kt) {
        __syncthreads();                      // tile kt staged (drains vmcnt)
        const int buf = kt & 1;

        if (kt + 1 <= kmax) {                 // prefetch next tile
            const int s0 = (kt + 1) * 64;
            const int nb = buf ^ 1;
            #pragma unroll
            for (int p = 0; p < 2; ++p) {
                gld16(K + ((size_t)s0 + w * 16 + p * 8 + lrow) * HD + lswz,
                      &Ks[nb][(w * 16 + p * 8) * 64]);
                gld16(Vt + (size_t)(w * 16 + p * 8 + lrow) * T_SEQ + s0 + lswz,
                      &Vs[nb][(w * 16 + p * 8) * 64]);
            }
        }

        // S^T = K Q^T : 2 s-tiles x 4 k-steps
        floatx16 sf[2];
        #pragma unroll
        for (int st = 0; st < 2; ++st)
            #pragma unroll
            for (int r = 0; r < 16; ++r) sf[st][r] = 0.0f;
        #pragma unroll
        for (int t = 0; t < 4; ++t)
            #pragma unroll
            for (int st = 0; st < 2; ++st) {
                const int row = st * 32 + nq;
                short8 a = *(const short8*)(
                    &Ks[buf][row * 64 + (((t * 2 + kh2) ^ (row & 7)) * 8)]);
                sf[st] = __builtin_amdgcn_mfma_f32_32x32x16_bf16(
                    a, qf[t], sf[st], 0, 0, 0);
            }

        // causal mask (diagonal vicinity only)
        const int sbase = kt * 64;
        if (sbase + 63 > qcol0) {
            const int qg = qcol0 + nq;
            #pragma unroll
            for (int st = 0; st < 2; ++st)
                #pragma unroll
                for (int r = 0; r < 16; ++r) {
                    int m = (r & 3) + 8 * (r >> 2) + 4 * kh2;
                    if (sbase + st * 32 + m > qg) sf[st][r] = -3.0e38f;
                }
        }

        // p = exp2(s); accumulate l per-lane; pack P^T into Ps[q][s]
        #pragma unroll
        for (int st = 0; st < 2; ++st)
            #pragma unroll
            for (int g = 0; g < 4; ++g) {
                float p0 = __builtin_amdgcn_exp2f(sf[st][4 * g + 0]);
                float p1 = __builtin_amdgcn_exp2f(sf[st][4 * g + 1]);
                float p2 = __builtin_amdgcn_exp2f(sf[st][4 * g + 2]);
                float p3 = __builtin_amdgcn_exp2f(sf[st][4 * g + 3]);
                l_acc += (p0 + p1) + (p2 + p3);
                uint2 u; u.x = pk2bf(p0, p1); u.y = pk2bf(p2, p3);
                *(uint2*)(&Ps[w * 32 + nq][st * 32 + 8 * g + 4 * kh2]) = u;
            }

        // O^T += V^T P^T : 2 d-tiles x 4 k-steps (B from Ps, same-wave rows)
        #pragma unroll
        for (int t = 0; t < 4; ++t) {
            short8 bpf = *(const short8*)(&Ps[w * 32 + nq][t * 16 + kh2 * 8]);
            #pragma unroll
            for (int dt = 0; dt < 2; ++dt) {
                const int row = dt * 32 + nq;
                short8 a = *(const short8*)(
                    &Vs[buf][row * 64 + (((t * 2 + kh2) ^ (row & 7)) * 8)]);
                Oa[dt] = __builtin_amdgcn_mfma_f32_32x32x16_bf16(
                    a, bpf, Oa[dt], 0, 0, 0);
            }
        }
    }

    // l is split across the two k-halves of each q-column: combine once
    float l_full = l_acc + __shfl_xor(l_acc, 32);
    float inv = 1.0f / l_full;

    // epilogue: O[q][d] bf16 via Ps (own rows), then coalesced store
    #pragma unroll
    for (int dt = 0; dt < 2; ++dt)
        #pragma unroll
        for (int g = 0; g < 4; ++g) {
            uint2 u;
            u.x = pk2bf(Oa[dt][4 * g + 0] * inv, Oa[dt][4 * g + 1] * inv);
            u.y = pk2bf(Oa[dt][4 * g + 2] * inv, Oa[dt][4 * g + 3] * inv);
            *(uint2*)(&Ps[w * 32 + nq][dt * 32 + 8 * g + 4 * kh2]) = u;
        }
    __syncthreads();
    #pragma unroll
    for (int p = 0; p < 4; ++p) {
        int idx = tid + 256 * p;              // 1024 chunks: q(128) x d-chunk(8)
        int r = idx >> 3, cc = idx & 7;
        short8 vv = *(const short8*)(&Ps[r][cc * 8]);
        *(short8*)(attb + ((size_t)(b * T_SEQ + qt * 128 + r)) * C_DIM + h * HD + cc * 8) = vv;
    }
}

// ---------------------------------------------------------------------------
// Output projection. Tile 128 x 64, BK=64. grid (32, 16).
// ---------------------------------------------------------------------------
__global__ __launch_bounds__(256) void proj_k(
    const short* __restrict__ attb, const short* __restrict__ wpt,
    const float* __restrict__ bp, float* __restrict__ out) {
    const int mt = blockIdx.x, nt_g = blockIdx.y;
    const int m0 = mt * 128, n0 = nt_g * 64;

    __shared__ short As[8192];
    __shared__ short Bs[4096];

    const int tid = threadIdx.x;
    const int lane = tid & 63, w = tid >> 6;
    const int hi = lane >> 4, llo = lane & 15;
    const int lrow = lane >> 3;
    const int lswz = ((lane & 7) ^ (lrow & 7)) * 8;
    const int fc0 = (hi ^ (llo & 7)) * 8;
    const int fc1 = ((hi + 4) ^ (llo & 7)) * 8;

    floatx4 acc[2][4];
    #pragma unroll
    for (int i = 0; i < 2; ++i)
        #pragma unroll
        for (int j = 0; j < 4; ++j)
            #pragma unroll
            for (int r = 0; r < 4; ++r) acc[i][j][r] = 0.0f;

    const size_t a_base = (size_t)(m0 + w * 32 + lrow) * C_DIM + lswz;
    const size_t b_base = (size_t)(n0 + w * 16 + lrow) * C_DIM + lswz;

    for (int kt = 0; kt < C_DIM / 64; ++kt) {
        const int c0 = kt * 64;
        __syncthreads();
        #pragma unroll
        for (int p = 0; p < 4; ++p)
            gld16(attb + a_base + (size_t)p * 8 * C_DIM + c0, &As[(w * 32 + p * 8) * 64]);
        #pragma unroll
        for (int p = 0; p < 2; ++p)
            gld16(wpt + b_base + (size_t)p * 8 * C_DIM + c0, &Bs[(w * 16 + p * 8) * 64]);
        __syncthreads();

        short8 af[2][2];
        #pragma unroll
        for (int m2 = 0; m2 < 2; ++m2) {
            const int row = w * 32 + m2 * 16 + llo;
            af[m2][0] = *(const short8*)(&As[row * 64 + fc0]);
            af[m2][1] = *(const short8*)(&As[row * 64 + fc1]);
        }
        #pragma unroll
        for (int nt = 0; nt < 4; ++nt) {
            const int row = nt * 16 + llo;
            short8 b0 = *(const short8*)(&Bs[row * 64 + fc0]);
            short8 b1 = *(const short8*)(&Bs[row * 64 + fc1]);
            #pragma unroll
            for (int m2 = 0; m2 < 2; ++m2) {
                acc[m2][nt] = __builtin_amdgcn_mfma_f32_16x16x32_bf16(af[m2][0], b0, acc[m2][nt], 0, 0, 0);
                acc[m2][nt] = __builtin_amdgcn_mfma_f32_16x16x32_bf16(af[m2][1], b1, acc[m2][nt], 0, 0, 0);
            }
        }
    }

    #pragma unroll
    for (int nt = 0; nt < 4; ++nt) {
        const int n = n0 + nt * 16 + llo;
        const float bias = bp[n];
        #pragma unroll
        for (int m2 = 0; m2 < 2; ++m2)
            #pragma unroll
            for (int r = 0; r < 4; ++r) {
                int m = m0 + w * 32 + m2 * 16 + hi * 4 + r;
                out[(size_t)m * C_DIM + n] = acc[m2][nt][r] + bias;
            }
    }
}

// ---------------------------------------------------------------------------
extern "C" void kernel_launch(void* const* d_in, const int* in_sizes, int n_in,
                              void* d_out, int out_size, void* d_ws, size_t ws_size,
                              hipStream_t stream) {
    const float* x  = (const float*)d_in[0];
    const float* Wq = (const float*)d_in[1];
    const float* Wk = (const float*)d_in[2];
    const float* Wv = (const float*)d_in[3];
    const float* Wp = (const float*)d_in[4];
    const float* bp = (const float*)d_in[5];
    float* out = (float*)d_out;

    short* xb   = (short*)d_ws;
    short* wt   = xb  + (size_t)M_TOT * C_DIM;
    short* wpt  = wt  + (size_t)3 * H_NUM * HD * C_DIM;
    short* qb   = wpt + (size_t)C_DIM * C_DIM;
    short* kb   = qb  + (size_t)M_TOT * C_DIM;
    short* vtb  = kb  + (size_t)M_TOT * C_DIM;
    short* attb = vtb + (size_t)M_TOT * C_DIM;

    prep_k<<<dim3(3072), 256, 0, stream>>>(x, Wq, Wk, Wv, Wp, xb, wt, wpt);
    qkv_k <<<dim3(M_TOT / 128, 3 * C_DIM / 128), 256, 0, stream>>>(xb, wt, qb, kb, vtb);
    attn_k<<<dim3(BH_N, T_SEQ / 128), 256, 0, stream>>>(qb, kb, vtb, attb);
    proj_k<<<dim3(M_TOT / 128, C_DIM / 64), 256, 0, stream>>>(attb, wpt, bp, out);
}